// Round 4
// baseline (967.860 us; speedup 1.0000x reference)
//
#include <hip/hip_runtime.h>
#include <stdint.h>

#define IN_DIM 512
#define OUT_DIM 64

typedef short bf16x8 __attribute__((ext_vector_type(8)));
typedef float f32x4 __attribute__((ext_vector_type(4)));
typedef _Float16 half4v __attribute__((ext_vector_type(4)));

__device__ inline unsigned short f2bf(float f) {          // RTN-even
    unsigned int u = __float_as_uint(f);
    return (unsigned short)((u + 0x7FFFu + ((u >> 16) & 1u)) >> 16);
}
__device__ inline float bf2f(unsigned short s) {
    return __uint_as_float(((unsigned int)s) << 16);
}

// ---------------- degree histogram (XCD-partitioned dest ranges) ----------------
__global__ void zero_deg_kernel(int* __restrict__ deg, int N) {
    int i = blockIdx.x * blockDim.x + threadIdx.x;
    if (i < N) deg[i] = 0;
}

__global__ __launch_bounds__(256) void hist_part_kernel(const int* __restrict__ col,
                                                        int* __restrict__ deg, int E, int N) {
    int part = blockIdx.x & 7;
    int lo = (int)((long)part * N / 8);
    int hi = (int)((long)(part + 1) * N / 8);
    int stride = (gridDim.x >> 3) * blockDim.x;
    int i = (blockIdx.x >> 3) * blockDim.x + threadIdx.x;
    for (; i < E; i += stride) {
        int c = col[i];
        if (c >= lo && c < hi) atomicAdd(&deg[c], 1);
    }
}

// dinv[i] = 1/sqrt(deg+1), d2[i] = 1/(deg+1)
__global__ void dinv_kernel(const int* __restrict__ deg, float* __restrict__ dinv,
                            float* __restrict__ d2, int N) {
    int i = blockIdx.x * blockDim.x + threadIdx.x;
    if (i < N) {
        float d = (float)deg[i] + 1.0f;
        dinv[i] = 1.0f / sqrtf(d);
        d2[i] = 1.0f / d;
    }
}

// ---------------- pack W into MFMA B-fragment layout, split hi/lo bf16 ----------------
__global__ void pack_w_kernel(const float* __restrict__ W,
                              unsigned short* __restrict__ Bhi,
                              unsigned short* __restrict__ Blo) {
    int tid = blockIdx.x * blockDim.x + threadIdx.x;  // 0..4095
    if (tid >= 4096) return;
    int L = tid & 63;
    int ct = tid >> 6;           // c*16 + t
    int t = ct & 15, c = ct >> 4;
    int o = c * 16 + (L & 15);
    int k0 = t * 32 + (L >> 4) * 8;
    const float* src = W + (size_t)o * IN_DIM + k0;
    #pragma unroll
    for (int j = 0; j < 8; ++j) {
        float w = src[j];
        unsigned short h = f2bf(w);
        Bhi[(size_t)tid * 8 + j] = h;
        Blo[(size_t)tid * 8 + j] = f2bf(w - bf2f(h));
    }
}

// ---------------- parallel exclusive scan: phase 1 (per-block local scan) ----------------
__global__ __launch_bounds__(1024) void scan_local_kernel(const int* __restrict__ deg,
                                                          int* __restrict__ rowptr,
                                                          int* __restrict__ bsum, int N) {
    __shared__ int sm[16];
    int tid = threadIdx.x, lane = tid & 63, wid = tid >> 6;
    int i = blockIdx.x * 4096 + tid * 4;
    int4 v = make_int4(0, 0, 0, 0);
    if (i + 3 < N) {
        v = *(const int4*)(deg + i);
    } else {
        if (i < N) v.x = deg[i];
        if (i + 1 < N) v.y = deg[i + 1];
        if (i + 2 < N) v.z = deg[i + 2];
        if (i + 3 < N) v.w = deg[i + 3];
    }
    int s1 = v.x, s2 = s1 + v.y, s3 = s2 + v.z, s4 = s3 + v.w;
    int incl = s4;
    #pragma unroll
    for (int d = 1; d < 64; d <<= 1) {
        int t = __shfl_up(incl, d, 64);
        if (lane >= d) incl += t;
    }
    if (lane == 63) sm[wid] = incl;
    __syncthreads();
    if (tid == 0) {
        int run = 0;
        #pragma unroll
        for (int w2 = 0; w2 < 16; ++w2) { int t = sm[w2]; sm[w2] = run; run += t; }
        bsum[blockIdx.x] = run;
    }
    __syncthreads();
    int tbase = incl - s4 + sm[wid];
    if (i + 3 < N) {
        *(int4*)(rowptr + i) = make_int4(tbase, tbase + s1, tbase + s2, tbase + s3);
    } else {
        if (i < N)     rowptr[i]     = tbase;
        if (i + 1 < N) rowptr[i + 1] = tbase + s1;
        if (i + 2 < N) rowptr[i + 2] = tbase + s2;
        if (i + 3 < N) rowptr[i + 3] = tbase + s3;
    }
}

// ---------------- scan phase 2: add block offsets, emit cursor copy ----------------
__global__ __launch_bounds__(1024) void scan_add_kernel(int* __restrict__ rowptr,
                                                        int* __restrict__ cursor,
                                                        const int* __restrict__ bsum,
                                                        int N, int nb) {
    __shared__ int soff;
    if (threadIdx.x == 0) {
        int off = 0;
        for (int j = 0; j < (int)blockIdx.x; ++j) off += bsum[j];
        soff = off;
        if ((int)blockIdx.x == nb - 1) {
            int tot = off;
            for (int j = blockIdx.x; j < nb; ++j) tot += bsum[j];
            rowptr[N] = tot;
        }
    }
    __syncthreads();
    int off = soff;
    int i = blockIdx.x * 4096 + threadIdx.x * 4;
    if (i + 3 < N) {
        int4 r = *(int4*)(rowptr + i);
        r.x += off; r.y += off; r.z += off; r.w += off;
        *(int4*)(rowptr + i) = r;
        *(int4*)(cursor + i) = r;
    } else {
        for (int j = 0; j < 4; ++j)
            if (i + j < N) { int r = rowptr[i + j] + off; rowptr[i + j] = r; cursor[i + j] = r; }
    }
}

// ---------------- CSC fill, XCD-partitioned dest ranges ----------------
__global__ __launch_bounds__(256) void fill_part_kernel(const int* __restrict__ row,
                                                        const int* __restrict__ col,
                                                        int* __restrict__ cursor,
                                                        int* __restrict__ csr, int E, int N) {
    int part = blockIdx.x & 7;
    int lo = (int)((long)part * N / 8);
    int hi = (int)((long)(part + 1) * N / 8);
    int stride = (gridDim.x >> 3) * blockDim.x;
    int i = (blockIdx.x >> 3) * blockDim.x + threadIdx.x;
    for (; i < E; i += stride) {
        int c = col[i];
        if (c >= lo && c < hi) {
            int pos = atomicAdd(&cursor[c], 1);
            csr[pos] = row[i];
        }
    }
}

// ---------------- MFMA GEMM: g0 = dinv * (x @ W^T + b), fp16 CHUNK-MAJOR output ----
// layout: h[(c*N + row)*16 + r16], c = col-tile 0..3 (==feature chunk), r16 = col&15
__global__ __launch_bounds__(256) void mfma_gemm_kernel(const float* __restrict__ x,
                                                        const unsigned short* __restrict__ Bhi,
                                                        const unsigned short* __restrict__ Blo,
                                                        const float* __restrict__ bias,
                                                        const float* __restrict__ dinv,
                                                        _Float16* __restrict__ h, int N) {
    int lane = threadIdx.x & 63;
    int wid  = __builtin_amdgcn_readfirstlane(threadIdx.x >> 6);
    int quad = lane >> 4, r16 = lane & 15;
    long rowBase = ((long)blockIdx.x * 4 + wid) * 32;
    if (rowBase >= N) return;
    bool full = (rowBase + 32 <= N);

    f32x4 acc[2][4];
    #pragma unroll
    for (int rt = 0; rt < 2; ++rt)
        #pragma unroll
        for (int c = 0; c < 4; ++c) acc[rt][c] = (f32x4){0.f, 0.f, 0.f, 0.f};

    int row0 = (int)rowBase + r16;
    int row1 = (int)rowBase + 16 + r16;
    int row0c = full ? row0 : (row0 < N ? row0 : N - 1);
    int row1c = full ? row1 : (row1 < N ? row1 : N - 1);
    const float* a0p = x + (size_t)row0c * IN_DIM + quad * 8;
    const float* a1p = x + (size_t)row1c * IN_DIM + quad * 8;

    for (int t = 0; t < 16; ++t) {
        bf16x8 bh[4], bl[4];
        #pragma unroll
        for (int c = 0; c < 4; ++c) {
            size_t off = ((size_t)(c * 16 + t) * 64 + lane) * 8;
            union { int4 i; bf16x8 b; } uh, ul;
            uh.i = *(const int4*)(Bhi + off);
            ul.i = *(const int4*)(Blo + off);
            bh[c] = uh.b; bl[c] = ul.b;
        }
        bf16x8 ah[2], al[2];
        #pragma unroll
        for (int rt = 0; rt < 2; ++rt) {
            const float* p = (rt ? a1p : a0p) + t * 32;
            float4 f0 = *(const float4*)p;
            float4 f1 = *(const float4*)(p + 4);
            float v[8] = {f0.x, f0.y, f0.z, f0.w, f1.x, f1.y, f1.z, f1.w};
            #pragma unroll
            for (int j = 0; j < 8; ++j) {
                unsigned short hi = f2bf(v[j]);
                ah[rt][j] = (short)hi;
                al[rt][j] = (short)f2bf(v[j] - bf2f(hi));
            }
        }
        #pragma unroll
        for (int rt = 0; rt < 2; ++rt)
            #pragma unroll
            for (int c = 0; c < 4; ++c) {
                acc[rt][c] = __builtin_amdgcn_mfma_f32_16x16x32_bf16(ah[rt], bh[c], acc[rt][c], 0, 0, 0);
                acc[rt][c] = __builtin_amdgcn_mfma_f32_16x16x32_bf16(ah[rt], bl[c], acc[rt][c], 0, 0, 0);
                acc[rt][c] = __builtin_amdgcn_mfma_f32_16x16x32_bf16(al[rt], bh[c], acc[rt][c], 0, 0, 0);
            }
    }

    float bb[4];
    #pragma unroll
    for (int c = 0; c < 4; ++c) bb[c] = bias[c * 16 + r16];
    #pragma unroll
    for (int rt = 0; rt < 2; ++rt)
        #pragma unroll
        for (int rr = 0; rr < 4; ++rr) {
            int row = (int)rowBase + rt * 16 + quad * 4 + rr;
            if (row < N) {
                float dv = dinv[row];
                #pragma unroll
                for (int c = 0; c < 4; ++c)
                    h[((size_t)c * N + row) * 16 + r16] =
                        (_Float16)(dv * (acc[rt][c][rr] + bb[c]));
            }
        }
}

// ---------------- one SpMM hop, L2-resident feature chunks ----------------
// 4 chunks x 16 fp16 features; chunk slice = N*32B = 3.2 MB, pinned to an XCD
// PAIR via (blockIdx&7)>>1 (8 MB combined L2).  csr read non-temporal, dst
// written non-temporal => slice is the only L2-cached data.  Persistent grid
// (2048 blocks = 8/CU, all co-resident) so block->XCD mapping cannot drift.
// Lane layout: el=lane>>2 edge slot (16), q=lane&3 feature quad (4 halfs).
// One gather instruction covers 16 edges; deg<=16 (56% of nodes) needs one.
#define HOP_K 8
#define HOP_BLOCKS 2048

__global__ __launch_bounds__(256) void hop_kernel(const _Float16* __restrict__ src,
                                                  _Float16* __restrict__ dst_h,
                                                  float* __restrict__ dst_f,
                                                  const int* __restrict__ csr,
                                                  const int* __restrict__ rowptr,
                                                  const float* __restrict__ scale,
                                                  int N, int finalOut) {
    int lane = threadIdx.x & 63;
    int wid  = __builtin_amdgcn_readfirstlane(threadIdx.x >> 6);
    int b    = blockIdx.x;
    int c    = (b & 7) >> 1;                 // feature chunk 0..3 == XCD pair
    int sub  = ((b >> 3) << 1) | (b & 1);    // 0..511 within chunk
    int el   = lane >> 2;                    // edge slot 0..15
    int q    = lane & 3;                     // feature quad 0..3

    const _Float16* cs = src + (size_t)c * N * 16;
    _Float16* cd = dst_h + (size_t)c * N * 16;   // unused when finalOut

    int nBlocks = (N + 4 * HOP_K - 1) / (4 * HOP_K);   // 3125
    for (int nb = sub; nb < nBlocks; nb += 512) {
        int n0 = nb * (4 * HOP_K) + wid * HOP_K;
        if (n0 >= N) continue;
        int nK = (N - n0 < HOP_K) ? (N - n0) : HOP_K;

        int rpv = 0;
        if (lane <= nK) rpv = rowptr[n0 + lane];

        for (int j = 0; j < nK; ++j) {
            int n = n0 + j;
            int s = __shfl(rpv, j, 64);
            int e = __shfl(rpv, j + 1, 64);
            int d = e - s;

            float a0 = 0.f, a1 = 0.f, a2 = 0.f, a3 = 0.f;
            if (d > 0) {
                int last = e - 1;
                int ad0 = s + el; if (ad0 > last) ad0 = last;
                int i0 = __builtin_nontemporal_load(csr + ad0);
                half4v v0 = *(const half4v*)(cs + (size_t)i0 * 16 + q * 4);
                if (el < d) {
                    a0 += (float)v0[0]; a1 += (float)v0[1];
                    a2 += (float)v0[2]; a3 += (float)v0[3];
                }
                if (d > 16) {
                    int ad1 = s + el + 16; if (ad1 > last) ad1 = last;
                    int i1 = __builtin_nontemporal_load(csr + ad1);
                    half4v v1 = *(const half4v*)(cs + (size_t)i1 * 16 + q * 4);
                    if (el + 16 < d) {
                        a0 += (float)v1[0]; a1 += (float)v1[1];
                        a2 += (float)v1[2]; a3 += (float)v1[3];
                    }
                    if (d > 32) {                  // Poisson-16 far tail
                        for (int i = s + 32; i < e; i += 16) {
                            int a = i + el; if (a > last) a = last;
                            int ii = __builtin_nontemporal_load(csr + a);
                            half4v v = *(const half4v*)(cs + (size_t)ii * 16 + q * 4);
                            if (i + el < e) {
                                a0 += (float)v[0]; a1 += (float)v[1];
                                a2 += (float)v[2]; a3 += (float)v[3];
                            }
                        }
                    }
                }
            }
            // reduce across 16 edge slots (xor strides 4..32)
            #pragma unroll
            for (int dd = 4; dd < 64; dd <<= 1) {
                a0 += __shfl_xor(a0, dd, 64);
                a1 += __shfl_xor(a1, dd, 64);
                a2 += __shfl_xor(a2, dd, 64);
                a3 += __shfl_xor(a3, dd, 64);
            }
            if (el == 0) {                       // lanes 0..3 hold quad q
                half4v s4 = *(const half4v*)(cs + (size_t)n * 16 + q * 4);
                float sc = scale[n];
                float r0 = (a0 + (float)s4[0]) * sc;
                float r1 = (a1 + (float)s4[1]) * sc;
                float r2 = (a2 + (float)s4[2]) * sc;
                float r3 = (a3 + (float)s4[3]) * sc;
                if (finalOut) {
                    f32x4 r = (f32x4){r0, r1, r2, r3};
                    *(f32x4*)(dst_f + (size_t)n * OUT_DIM + c * 16 + q * 4) = r;
                } else {
                    half4v o;
                    o[0] = (_Float16)r0; o[1] = (_Float16)r1;
                    o[2] = (_Float16)r2; o[3] = (_Float16)r3;
                    __builtin_nontemporal_store(o, (half4v*)(cd + (size_t)n * 16 + q * 4));
                }
            }
        }
    }
}

extern "C" void kernel_launch(void* const* d_in, const int* in_sizes, int n_in,
                              void* d_out, int out_size, void* d_ws, size_t ws_size,
                              hipStream_t stream) {
    const float* x  = (const float*)d_in[0];
    const float* W  = (const float*)d_in[1];
    const float* b  = (const float*)d_in[2];
    const int*   ei = (const int*)d_in[3];
    int N = in_sizes[0] / IN_DIM;   // 100000
    int E = in_sizes[3] / 2;        // 1.6M
    const int* row = ei;
    const int* col = ei + E;
    float* out = (float*)d_out;

    // ---- small scratch in d_ws (~2.2 MB) ----
    float* dinv   = (float*)d_ws;                    // N
    float* d2     = dinv + N;                        // N
    int*   deg    = (int*)(d2 + N);                  // N
    int*   rowptr = deg + N;                         // N+4
    int*   cursor = rowptr + (N + 4);                // N
    int*   bsum   = cursor + N;                      // 32 (scan block sums)
    unsigned short* Bhi = (unsigned short*)(bsum + 32);    // 32768 (64 KB)
    unsigned short* Blo = Bhi + 32768;                     // 32768 (64 KB)

    // ---- fp16 ping-pong buffers (chunk-major [4][N][16]) ----
    // g0/g2 in the LOW HALF of d_out (12.8 MB of 25.6) — written by gemm, no
    // write-into-unread-x hazard.  g1/g3 + csr in x-space, carved only AFTER
    // gemm has fully consumed x (stream-serialized).
    _Float16* gout = (_Float16*)d_out;                        // N*64 halfs (12.8 MB)
    float* xspace = (float*)d_in[0];
    _Float16* gx   = (_Float16*)xspace;                       // N*64 halfs (12.8 MB)
    int* csr = (int*)((char*)xspace + (size_t)N * OUT_DIM * sizeof(_Float16)); // E ints

    dim3 blk(256);
    int gN = (N + 255) / 256;
    int gPart = 8 * 784;              // 8 XCD-parts x 784 blocks
    int nbScan = (N + 4095) / 4096;   // 25

    // 1) degrees + dinv/d2 (reads edge_index only)
    zero_deg_kernel<<<gN, blk, 0, stream>>>(deg, N);
    hist_part_kernel<<<gPart, blk, 0, stream>>>(col, deg, E, N);
    dinv_kernel<<<gN, blk, 0, stream>>>(deg, dinv, d2, N);

    // 2) pack W into split-bf16 MFMA B-fragments
    pack_w_kernel<<<16, blk, 0, stream>>>(W, Bhi, Blo);

    // 3) MFMA GEMM consumes x completely; epilogue pre-scales by dinv,
    //    writes fp16 g0 chunk-major -> low half of d_out
    mfma_gemm_kernel<<<(N + 127) / 128, blk, 0, stream>>>(x, Bhi, Blo, b, dinv, gout, N);

    // 4) CSC build (after gemm in stream order; csr lives in x-space)
    scan_local_kernel<<<nbScan, 1024, 0, stream>>>(deg, rowptr, bsum, N);
    scan_add_kernel<<<nbScan, 1024, 0, stream>>>(rowptr, cursor, bsum, N, nbScan);
    fill_part_kernel<<<gPart, blk, 0, stream>>>(row, col, cursor, csr, E, N);

    // 5) 4 hops; fp16 chunk-major intermediates; last hop applies dinv and
    //    writes fp32 row-major h4 -> d_out
    hop_kernel<<<HOP_BLOCKS, blk, 0, stream>>>(gout, gx,   nullptr, csr, rowptr, d2,   N, 0); // g1
    hop_kernel<<<HOP_BLOCKS, blk, 0, stream>>>(gx,   gout, nullptr, csr, rowptr, d2,   N, 0); // g2
    hop_kernel<<<HOP_BLOCKS, blk, 0, stream>>>(gout, gx,   nullptr, csr, rowptr, d2,   N, 0); // g3
    hop_kernel<<<HOP_BLOCKS, blk, 0, stream>>>(gx, gout,   out,     csr, rowptr, dinv, N, 1); // h4
}

// Round 5
// 642.787 us; speedup vs baseline: 1.5057x; 1.5057x over previous
//
#include <hip/hip_runtime.h>
#include <stdint.h>

#define IN_DIM 512
#define OUT_DIM 64

typedef short bf16x8 __attribute__((ext_vector_type(8)));
typedef float f32x4 __attribute__((ext_vector_type(4)));
typedef _Float16 half8v __attribute__((ext_vector_type(8)));

__device__ inline unsigned short f2bf(float f) {          // RTN-even
    unsigned int u = __float_as_uint(f);
    return (unsigned short)((u + 0x7FFFu + ((u >> 16) & 1u)) >> 16);
}
__device__ inline float bf2f(unsigned short s) {
    return __uint_as_float(((unsigned int)s) << 16);
}

// ---------------- degree histogram (XCD-partitioned dest ranges) ----------------
__global__ void zero_deg_kernel(int* __restrict__ deg, int N) {
    int i = blockIdx.x * blockDim.x + threadIdx.x;
    if (i < N) deg[i] = 0;
}

__global__ __launch_bounds__(256) void hist_part_kernel(const int* __restrict__ col,
                                                        int* __restrict__ deg, int E, int N) {
    int part = blockIdx.x & 7;
    int lo = (int)((long)part * N / 8);
    int hi = (int)((long)(part + 1) * N / 8);
    int stride = (gridDim.x >> 3) * blockDim.x;
    int i = (blockIdx.x >> 3) * blockDim.x + threadIdx.x;
    for (; i < E; i += stride) {
        int c = col[i];
        if (c >= lo && c < hi) atomicAdd(&deg[c], 1);
    }
}

// dinv[i] = 1/sqrt(deg+1), d2[i] = 1/(deg+1)
__global__ void dinv_kernel(const int* __restrict__ deg, float* __restrict__ dinv,
                            float* __restrict__ d2, int N) {
    int i = blockIdx.x * blockDim.x + threadIdx.x;
    if (i < N) {
        float d = (float)deg[i] + 1.0f;
        dinv[i] = 1.0f / sqrtf(d);
        d2[i] = 1.0f / d;
    }
}

// ---------------- pack W into MFMA B-fragment layout, split hi/lo bf16 ----------------
__global__ void pack_w_kernel(const float* __restrict__ W,
                              unsigned short* __restrict__ Bhi,
                              unsigned short* __restrict__ Blo) {
    int tid = blockIdx.x * blockDim.x + threadIdx.x;  // 0..4095
    if (tid >= 4096) return;
    int L = tid & 63;
    int ct = tid >> 6;           // c*16 + t
    int t = ct & 15, c = ct >> 4;
    int o = c * 16 + (L & 15);
    int k0 = t * 32 + (L >> 4) * 8;
    const float* src = W + (size_t)o * IN_DIM + k0;
    #pragma unroll
    for (int j = 0; j < 8; ++j) {
        float w = src[j];
        unsigned short h = f2bf(w);
        Bhi[(size_t)tid * 8 + j] = h;
        Blo[(size_t)tid * 8 + j] = f2bf(w - bf2f(h));
    }
}

// ---------------- parallel exclusive scan: phase 1 (per-block local scan) ----------------
__global__ __launch_bounds__(1024) void scan_local_kernel(const int* __restrict__ deg,
                                                          int* __restrict__ rowptr,
                                                          int* __restrict__ bsum, int N) {
    __shared__ int sm[16];
    int tid = threadIdx.x, lane = tid & 63, wid = tid >> 6;
    int i = blockIdx.x * 4096 + tid * 4;
    int4 v = make_int4(0, 0, 0, 0);
    if (i + 3 < N) {
        v = *(const int4*)(deg + i);
    } else {
        if (i < N) v.x = deg[i];
        if (i + 1 < N) v.y = deg[i + 1];
        if (i + 2 < N) v.z = deg[i + 2];
        if (i + 3 < N) v.w = deg[i + 3];
    }
    int s1 = v.x, s2 = s1 + v.y, s3 = s2 + v.z, s4 = s3 + v.w;
    int incl = s4;
    #pragma unroll
    for (int d = 1; d < 64; d <<= 1) {
        int t = __shfl_up(incl, d, 64);
        if (lane >= d) incl += t;
    }
    if (lane == 63) sm[wid] = incl;
    __syncthreads();
    if (tid == 0) {
        int run = 0;
        #pragma unroll
        for (int w2 = 0; w2 < 16; ++w2) { int t = sm[w2]; sm[w2] = run; run += t; }
        bsum[blockIdx.x] = run;
    }
    __syncthreads();
    int tbase = incl - s4 + sm[wid];
    if (i + 3 < N) {
        *(int4*)(rowptr + i) = make_int4(tbase, tbase + s1, tbase + s2, tbase + s3);
    } else {
        if (i < N)     rowptr[i]     = tbase;
        if (i + 1 < N) rowptr[i + 1] = tbase + s1;
        if (i + 2 < N) rowptr[i + 2] = tbase + s2;
        if (i + 3 < N) rowptr[i + 3] = tbase + s3;
    }
}

// ---------------- scan phase 2: add block offsets, emit cursor copy ----------------
__global__ __launch_bounds__(1024) void scan_add_kernel(int* __restrict__ rowptr,
                                                        int* __restrict__ cursor,
                                                        const int* __restrict__ bsum,
                                                        int N, int nb) {
    __shared__ int soff;
    if (threadIdx.x == 0) {
        int off = 0;
        for (int j = 0; j < (int)blockIdx.x; ++j) off += bsum[j];
        soff = off;
        if ((int)blockIdx.x == nb - 1) {
            int tot = off;
            for (int j = blockIdx.x; j < nb; ++j) tot += bsum[j];
            rowptr[N] = tot;
        }
    }
    __syncthreads();
    int off = soff;
    int i = blockIdx.x * 4096 + threadIdx.x * 4;
    if (i + 3 < N) {
        int4 r = *(int4*)(rowptr + i);
        r.x += off; r.y += off; r.z += off; r.w += off;
        *(int4*)(rowptr + i) = r;
        *(int4*)(cursor + i) = r;
    } else {
        for (int j = 0; j < 4; ++j)
            if (i + j < N) { int r = rowptr[i + j] + off; rowptr[i + j] = r; cursor[i + j] = r; }
    }
}

// ---------------- CSC fill, XCD-partitioned dest ranges ----------------
__global__ __launch_bounds__(256) void fill_part_kernel(const int* __restrict__ row,
                                                        const int* __restrict__ col,
                                                        int* __restrict__ cursor,
                                                        int* __restrict__ csr, int E, int N) {
    int part = blockIdx.x & 7;
    int lo = (int)((long)part * N / 8);
    int hi = (int)((long)(part + 1) * N / 8);
    int stride = (gridDim.x >> 3) * blockDim.x;
    int i = (blockIdx.x >> 3) * blockDim.x + threadIdx.x;
    for (; i < E; i += stride) {
        int c = col[i];
        if (c >= lo && c < hi) {
            int pos = atomicAdd(&cursor[c], 1);
            csr[pos] = row[i];
        }
    }
}

// ---------------- MFMA GEMM: g0 = dinv * (x @ W^T + b), fp16 output ----------------
__global__ __launch_bounds__(256) void mfma_gemm_kernel(const float* __restrict__ x,
                                                        const unsigned short* __restrict__ Bhi,
                                                        const unsigned short* __restrict__ Blo,
                                                        const float* __restrict__ bias,
                                                        const float* __restrict__ dinv,
                                                        _Float16* __restrict__ h, int N) {
    int lane = threadIdx.x & 63;
    int wid  = __builtin_amdgcn_readfirstlane(threadIdx.x >> 6);
    int quad = lane >> 4, r16 = lane & 15;
    long rowBase = ((long)blockIdx.x * 4 + wid) * 32;
    if (rowBase >= N) return;
    bool full = (rowBase + 32 <= N);

    f32x4 acc[2][4];
    #pragma unroll
    for (int rt = 0; rt < 2; ++rt)
        #pragma unroll
        for (int c = 0; c < 4; ++c) acc[rt][c] = (f32x4){0.f, 0.f, 0.f, 0.f};

    int row0 = (int)rowBase + r16;
    int row1 = (int)rowBase + 16 + r16;
    int row0c = full ? row0 : (row0 < N ? row0 : N - 1);
    int row1c = full ? row1 : (row1 < N ? row1 : N - 1);
    const float* a0p = x + (size_t)row0c * IN_DIM + quad * 8;
    const float* a1p = x + (size_t)row1c * IN_DIM + quad * 8;

    for (int t = 0; t < 16; ++t) {
        bf16x8 bh[4], bl[4];
        #pragma unroll
        for (int c = 0; c < 4; ++c) {
            size_t off = ((size_t)(c * 16 + t) * 64 + lane) * 8;
            union { int4 i; bf16x8 b; } uh, ul;
            uh.i = *(const int4*)(Bhi + off);
            ul.i = *(const int4*)(Blo + off);
            bh[c] = uh.b; bl[c] = ul.b;
        }
        bf16x8 ah[2], al[2];
        #pragma unroll
        for (int rt = 0; rt < 2; ++rt) {
            const float* p = (rt ? a1p : a0p) + t * 32;
            float4 f0 = *(const float4*)p;
            float4 f1 = *(const float4*)(p + 4);
            float v[8] = {f0.x, f0.y, f0.z, f0.w, f1.x, f1.y, f1.z, f1.w};
            #pragma unroll
            for (int j = 0; j < 8; ++j) {
                unsigned short hi = f2bf(v[j]);
                ah[rt][j] = (short)hi;
                al[rt][j] = (short)f2bf(v[j] - bf2f(hi));
            }
        }
        #pragma unroll
        for (int rt = 0; rt < 2; ++rt)
            #pragma unroll
            for (int c = 0; c < 4; ++c) {
                acc[rt][c] = __builtin_amdgcn_mfma_f32_16x16x32_bf16(ah[rt], bh[c], acc[rt][c], 0, 0, 0);
                acc[rt][c] = __builtin_amdgcn_mfma_f32_16x16x32_bf16(ah[rt], bl[c], acc[rt][c], 0, 0, 0);
                acc[rt][c] = __builtin_amdgcn_mfma_f32_16x16x32_bf16(al[rt], bh[c], acc[rt][c], 0, 0, 0);
            }
    }

    float bb[4];
    #pragma unroll
    for (int c = 0; c < 4; ++c) bb[c] = bias[c * 16 + r16];
    #pragma unroll
    for (int rt = 0; rt < 2; ++rt)
        #pragma unroll
        for (int rr = 0; rr < 4; ++rr) {
            int row = (int)rowBase + rt * 16 + quad * 4 + rr;
            if (row < N) {
                float dv = dinv[row];
                #pragma unroll
                for (int c = 0; c < 4; ++c)
                    h[(size_t)row * OUT_DIM + c * 16 + r16] =
                        (_Float16)(dv * (acc[rt][c][rr] + bb[c]));
            }
        }
}

// ---------------- one SpMM hop, fp16 rows, 16B-per-lane gathers ----------------
// Address-rate model (r0/r1/r3/r4 invariant): hop time ~ per-lane VMEM address
// count.  fp16 row = 128 B = 8 lanes x half8 (16 B, dwordx4) = 8 addr/row — half
// of every previous design.  Wave = 8 edge-slots (g) x 8 feature-lanes (f8);
// one gather instruction fetches 8 full rows; deg<=16 needs 2.
#define HOP_K 8

__global__ __launch_bounds__(256) void hop_kernel(const _Float16* __restrict__ src,
                                                  _Float16* __restrict__ dst_h,
                                                  float* __restrict__ dst_f,
                                                  const int* __restrict__ csr,
                                                  const int* __restrict__ rowptr,
                                                  const float* __restrict__ scale,
                                                  int N, int finalOut) {
    int lane = threadIdx.x & 63;
    int wid  = __builtin_amdgcn_readfirstlane(threadIdx.x >> 6);
    int g    = lane >> 3;       // edge slot 0..7
    int f8   = lane & 7;        // 16B feature slot 0..7 (8 halfs)
    int w  = blockIdx.x * 4 + wid;
    int n0 = w * HOP_K;
    if (n0 >= N) return;
    int nK = (N - n0 < HOP_K) ? (N - n0) : HOP_K;

    int rpv = 0;
    if (lane <= nK) rpv = rowptr[n0 + lane];

    for (int j = 0; j < nK; ++j) {
        int n = n0 + j;
        int s = __shfl(rpv, j, 64);
        int e = __shfl(rpv, j + 1, 64);

        float a[8];
        #pragma unroll
        for (int k = 0; k < 8; ++k) a[k] = 0.f;

        int i = s;
        // main: 16 edges/iter; slot g owns edges i+g and i+8+g
        for (; i + 16 <= e; i += 16) {
            int i0 = csr[i + g];
            int i1 = csr[i + 8 + g];
            half8v v0 = *(const half8v*)(src + (size_t)i0 * OUT_DIM + f8 * 8);
            half8v v1 = *(const half8v*)(src + (size_t)i1 * OUT_DIM + f8 * 8);
            #pragma unroll
            for (int k = 0; k < 8; ++k) a[k] += (float)v0[k] + (float)v1[k];
        }
        // mid: 8 edges/iter
        for (; i + 8 <= e; i += 8) {
            int i0 = csr[i + g];
            half8v v = *(const half8v*)(src + (size_t)i0 * OUT_DIM + f8 * 8);
            #pragma unroll
            for (int k = 0; k < 8; ++k) a[k] += (float)v[k];
        }
        // tail: remaining (e-i) in [0,8); slots g < e-i take one edge
        if (i + g < e) {
            int i0 = csr[i + g];
            half8v v = *(const half8v*)(src + (size_t)i0 * OUT_DIM + f8 * 8);
            #pragma unroll
            for (int k = 0; k < 8; ++k) a[k] += (float)v[k];
        }
        // reduce across the 8 edge slots (xor 8, 16, 32)
        #pragma unroll
        for (int d = 8; d < 64; d <<= 1)
            #pragma unroll
            for (int k = 0; k < 8; ++k) a[k] += __shfl_xor(a[k], d, 64);

        if (g == 0) {                      // lanes 0..7, one 16B slot each
            half8v s8 = *(const half8v*)(src + (size_t)n * OUT_DIM + f8 * 8);
            float sc = scale[n];
            if (finalOut) {
                f32x4 r0, r1;
                #pragma unroll
                for (int k = 0; k < 4; ++k) r0[k] = (a[k] + (float)s8[k]) * sc;
                #pragma unroll
                for (int k = 0; k < 4; ++k) r1[k] = (a[k + 4] + (float)s8[k + 4]) * sc;
                *(f32x4*)(dst_f + (size_t)n * OUT_DIM + f8 * 8) = r0;
                *(f32x4*)(dst_f + (size_t)n * OUT_DIM + f8 * 8 + 4) = r1;
            } else {
                half8v o;
                #pragma unroll
                for (int k = 0; k < 8; ++k) o[k] = (_Float16)((a[k] + (float)s8[k]) * sc);
                *(half8v*)(dst_h + (size_t)n * OUT_DIM + f8 * 8) = o;
            }
        }
    }
}

extern "C" void kernel_launch(void* const* d_in, const int* in_sizes, int n_in,
                              void* d_out, int out_size, void* d_ws, size_t ws_size,
                              hipStream_t stream) {
    const float* x  = (const float*)d_in[0];
    const float* W  = (const float*)d_in[1];
    const float* b  = (const float*)d_in[2];
    const int*   ei = (const int*)d_in[3];
    int N = in_sizes[0] / IN_DIM;   // 100000
    int E = in_sizes[3] / 2;        // 1.6M
    const int* row = ei;
    const int* col = ei + E;
    float* out = (float*)d_out;

    // ---- small scratch in d_ws (~2.2 MB) ----
    float* dinv   = (float*)d_ws;                    // N
    float* d2     = dinv + N;                        // N
    int*   deg    = (int*)(d2 + N);                  // N
    int*   rowptr = deg + N;                         // N+4
    int*   cursor = rowptr + (N + 4);                // N
    int*   bsum   = cursor + N;                      // 32 (scan block sums)
    unsigned short* Bhi = (unsigned short*)(bsum + 32);    // 32768 (64 KB)
    unsigned short* Blo = Bhi + 32768;                     // 32768 (64 KB)

    // ---- fp16 ping-pong buffers ----
    // g0/g2 live in the LOW HALF of d_out (12.8 MB of its 25.6 MB) — written by
    // gemm, so no write-into-unread-x hazard.  g1/g3 + csr live in x-space,
    // carved only AFTER gemm has fully consumed x (stream-serialized).
    _Float16* gout = (_Float16*)d_out;                        // N*64 halfs (12.8 MB)
    float* xspace = (float*)d_in[0];
    _Float16* gx   = (_Float16*)xspace;                       // N*64 halfs (12.8 MB)
    int* csr = (int*)((char*)xspace + (size_t)N * OUT_DIM * sizeof(_Float16)); // E ints

    dim3 blk(256);
    int gN = (N + 255) / 256;
    int gPart = 8 * 784;              // 8 XCD-parts x 784 blocks
    int nbScan = (N + 4095) / 4096;   // 25

    // 1) degrees + dinv/d2 (reads edge_index only)
    zero_deg_kernel<<<gN, blk, 0, stream>>>(deg, N);
    hist_part_kernel<<<gPart, blk, 0, stream>>>(col, deg, E, N);
    dinv_kernel<<<gN, blk, 0, stream>>>(deg, dinv, d2, N);

    // 2) pack W into split-bf16 MFMA B-fragments
    pack_w_kernel<<<16, blk, 0, stream>>>(W, Bhi, Blo);

    // 3) MFMA GEMM consumes x completely; epilogue pre-scales by dinv,
    //    writes fp16 g0 -> low half of d_out
    mfma_gemm_kernel<<<(N + 127) / 128, blk, 0, stream>>>(x, Bhi, Blo, b, dinv, gout, N);

    // 4) CSC build (after gemm in stream order; csr lives in x-space)
    scan_local_kernel<<<nbScan, 1024, 0, stream>>>(deg, rowptr, bsum, N);
    scan_add_kernel<<<nbScan, 1024, 0, stream>>>(rowptr, cursor, bsum, N, nbScan);
    fill_part_kernel<<<gPart, blk, 0, stream>>>(row, col, cursor, csr, E, N);

    // 5) 4 hops; intermediates fp16; last hop applies dinv and writes fp32 h4
    int chunks = (N + HOP_K - 1) / HOP_K;
    int gH = (chunks + 3) / 4;
    hop_kernel<<<gH, blk, 0, stream>>>(gout, gx,   nullptr, csr, rowptr, d2,   N, 0); // g1
    hop_kernel<<<gH, blk, 0, stream>>>(gx,   gout, nullptr, csr, rowptr, d2,   N, 0); // g2
    hop_kernel<<<gH, blk, 0, stream>>>(gout, gx,   nullptr, csr, rowptr, d2,   N, 0); // g3
    hop_kernel<<<gH, blk, 0, stream>>>(gx, nullptr, out,    csr, rowptr, dinv, N, 1); // h4
}